// Round 11
// baseline (123.659 us; speedup 1.0000x reference)
//
#include <hip/hip_runtime.h>

// Single-query cross-attention, algebraically collapsed:
//   scores[h,l] = (scale*Wk_h^T q_h) . x[l]      (k-bias cancels in softmax)
//   out_attn[h] = Wv_h @ (sum_l softmax_w[l] * x[l]) + bv_h
// => one streaming pass over x (64 MB), memory-bound.
// R10: k_main split into two passes per block — Pass A: scores only (xr dead
// after dots -> deep load pipelining; w -> 512B LDS). Pass B: re-read rows
// (L2-hot) and pure-FMA weighted accumulate, no cross-lane ops, no rotation.
// Breaks the per-row load->shfl-tree->exp->FMA serial chain that kept
// measured BW ~3x below the stream floor.

#define DIM   512
#define NH    4
#define HDIM  128
#define SCALE 0.08838834764831845f  // 1/sqrt(128)

#define NB              1024
#define ROWS_PER_BLOCK  32
#define ROWS_PER_WAVE   8
#define NSLOT           32

// ws layout (float offsets). Total 68736 floats ~ 275 KB.
#define WS_Q     0      // 512
#define WS_QKS   512    // NH*DIM = 2048 (scale * Wk_h^T q_h), atomic-accumulated
#define WS_ATTN  2560   // 512
#define WS_S     3072   // NSLOT*NH = 128 softmax denominators
#define WS_XA    3200   // NSLOT*NH*DIM = 65536 weighted x-sum slots

// 512 blocks x 1 wave: one wave per output d; also zeros all accumulators.
__global__ __launch_bounds__(64)
void k_qproj(const float* __restrict__ x, const float* __restrict__ ipw,
             const float* __restrict__ ipb, float* __restrict__ ws) {
  const int g = blockIdx.x * 64 + threadIdx.x;  // 0..32767
  ws[WS_XA + g] = 0.f;
  ws[WS_XA + 32768 + g] = 0.f;                  // 65536 = NSLOT*NH*DIM total
  if (g < NSLOT * NH) ws[WS_S + g]   = 0.f;
  if (g < NH * DIM)   ws[WS_QKS + g] = 0.f;

  const int lane = threadIdx.x;
  const int d = blockIdx.x;  // 0..511
  const float4 xa = *(const float4*)(x + lane * 8);
  const float4 xb = *(const float4*)(x + lane * 8 + 4);
  const float* wr = ipw + (size_t)d * DIM + lane * 8;
  const float4 wa = *(const float4*)wr;
  const float4 wb = *(const float4*)(wr + 4);
  float acc = wa.x*xa.x + wa.y*xa.y + wa.z*xa.z + wa.w*xa.w
            + wb.x*xb.x + wb.y*xb.y + wb.z*xb.z + wb.w*xb.w;
  #pragma unroll
  for (int off = 32; off; off >>= 1) acc += __shfl_xor(acc, off, 64);
  if (lane == 0) ws[WS_Q + d] = acc + ipb[d];
}

// 256 blocks x 1 wave: wave = (64-output chunk o) x (16-wide hd eighth).
// Coalesced 256B row-chunk loads; 8 atomicAdds per output address.
__global__ __launch_bounds__(64)
void k_qk(const float* __restrict__ ipw, float* __restrict__ ws) {
  const int lane = threadIdx.x;
  const int W  = blockIdx.x;             // 0..255
  const int o  = W & 31;                 // output chunk (64 outputs)
  const int he = W >> 5;                 // hd eighth (16 rows)
  const int h  = o >> 3;
  const int col = o * 64 + lane;         // flat out index = h*512 + dp
  const int dp  = col & 511;
  const float* q = ws + WS_Q + h * HDIM + he * 16;
  const float* wbase = ipw + (size_t)(DIM + h * HDIM + he * 16) * DIM + dp;
  float acc = 0.f;
  #pragma unroll
  for (int i = 0; i < 16; ++i)
    acc += q[i] * wbase[(size_t)i * DIM];
  atomicAdd(ws + WS_QKS + col, acc * SCALE);
}

// Main pass, two-phase:
//  A: per row, dots -> 4x4 lane transpose -> butterfly -> exp -> w to LDS.
//  B: re-read rows (L2-hot), xacc[h] += w[r][h]*xr  (pure FMA, no shuffles).
// LDS 2-buffer combine; striped atomicAdd into xA/S slots.
__global__ __launch_bounds__(256, 4)
void k_main(const float* __restrict__ x, float* __restrict__ ws) {
  const int wave = threadIdx.x >> 6, lane = threadIdx.x & 63;
  const bool b1 = lane & 1, b2 = lane & 2;
  const int row0 = blockIdx.x * ROWS_PER_BLOCK + wave * ROWS_PER_WAVE;

  __shared__ float lds_w[ROWS_PER_BLOCK][NH];   // 512 B
  __shared__ float lds_xa[2][NH * DIM];         // 16 KB
  __shared__ float lds_s[4][NH];

  float qk[NH][8];
  #pragma unroll
  for (int h = 0; h < NH; ++h) {
    const float4 a = *(const float4*)(ws + WS_QKS + h * DIM + lane * 8);
    const float4 b = *(const float4*)(ws + WS_QKS + h * DIM + lane * 8 + 4);
    qk[h][0]=a.x; qk[h][1]=a.y; qk[h][2]=a.z; qk[h][3]=a.w;
    qk[h][4]=b.x; qk[h][5]=b.y; qk[h][6]=b.z; qk[h][7]=b.w;
  }

  const float* xp = x + (size_t)row0 * DIM + lane * 8;
  float s = 0.f;   // denominator of head (lane&3)

  // ---- Pass A: scores ----
  #pragma unroll
  for (int r = 0; r < ROWS_PER_WAVE; ++r) {
    const float* rp = xp + (size_t)r * DIM;
    const float4 a = *(const float4*)rp;
    const float4 b = *(const float4*)(rp + 4);
    float d0 = qk[0][0]*a.x + qk[0][1]*a.y + qk[0][2]*a.z + qk[0][3]*a.w
             + qk[0][4]*b.x + qk[0][5]*b.y + qk[0][6]*b.z + qk[0][7]*b.w;
    float d1 = qk[1][0]*a.x + qk[1][1]*a.y + qk[1][2]*a.z + qk[1][3]*a.w
             + qk[1][4]*b.x + qk[1][5]*b.y + qk[1][6]*b.z + qk[1][7]*b.w;
    float d2 = qk[2][0]*a.x + qk[2][1]*a.y + qk[2][2]*a.z + qk[2][3]*a.w
             + qk[2][4]*b.x + qk[2][5]*b.y + qk[2][6]*b.z + qk[2][7]*b.w;
    float d3 = qk[3][0]*a.x + qk[3][1]*a.y + qk[3][2]*a.z + qk[3][3]*a.w
             + qk[3][4]*b.x + qk[3][5]*b.y + qk[3][6]*b.z + qk[3][7]*b.w;
    // 4x4 transpose-reduce within 4-lane groups -> lane holds head (l&3) partial
    const float x01 = b1 ? d0 : d1;
    const float x23 = b1 ? d2 : d3;
    const float A = (b1 ? d1 : d0) + __shfl_xor(x01, 1, 64);
    const float B = (b1 ? d3 : d2) + __shfl_xor(x23, 1, 64);
    const float y = b2 ? A : B;
    float v = (b2 ? B : A) + __shfl_xor(y, 2, 64);
    v += __shfl_xor(v, 4, 64);
    v += __shfl_xor(v, 8, 64);
    v += __shfl_xor(v, 16, 64);
    v += __shfl_xor(v, 32, 64);
    const float w0 = __expf(v);   // lane's head (l&3)
    s += w0;
    if (lane < NH) lds_w[wave * ROWS_PER_WAVE + r][lane] = w0;
  }
  if (lane < NH) lds_s[wave][lane] = s;
  __syncthreads();

  // ---- Pass B: weighted accumulate (rows are L2-hot) ----
  float xacc[NH][8];
  #pragma unroll
  for (int h = 0; h < NH; ++h)
    #pragma unroll
    for (int j = 0; j < 8; ++j) xacc[h][j] = 0.f;

  #pragma unroll
  for (int r = 0; r < ROWS_PER_WAVE; ++r) {
    const float* rp = xp + (size_t)r * DIM;
    const float4 a = *(const float4*)rp;
    const float4 b = *(const float4*)(rp + 4);
    const float w0 = lds_w[wave * ROWS_PER_WAVE + r][0];
    const float w1 = lds_w[wave * ROWS_PER_WAVE + r][1];
    const float w2 = lds_w[wave * ROWS_PER_WAVE + r][2];
    const float w3 = lds_w[wave * ROWS_PER_WAVE + r][3];
    xacc[0][0]+=w0*a.x; xacc[0][1]+=w0*a.y; xacc[0][2]+=w0*a.z; xacc[0][3]+=w0*a.w;
    xacc[0][4]+=w0*b.x; xacc[0][5]+=w0*b.y; xacc[0][6]+=w0*b.z; xacc[0][7]+=w0*b.w;
    xacc[1][0]+=w1*a.x; xacc[1][1]+=w1*a.y; xacc[1][2]+=w1*a.z; xacc[1][3]+=w1*a.w;
    xacc[1][4]+=w1*b.x; xacc[1][5]+=w1*b.y; xacc[1][6]+=w1*b.z; xacc[1][7]+=w1*b.w;
    xacc[2][0]+=w2*a.x; xacc[2][1]+=w2*a.y; xacc[2][2]+=w2*a.z; xacc[2][3]+=w2*a.w;
    xacc[2][4]+=w2*b.x; xacc[2][5]+=w2*b.y; xacc[2][6]+=w2*b.z; xacc[2][7]+=w2*b.w;
    xacc[3][0]+=w3*a.x; xacc[3][1]+=w3*a.y; xacc[3][2]+=w3*a.z; xacc[3][3]+=w3*a.w;
    xacc[3][4]+=w3*b.x; xacc[3][5]+=w3*b.y; xacc[3][6]+=w3*b.z; xacc[3][7]+=w3*b.w;
  }

  // 2-buffer combine: waves 2,3 store; waves 0,1 add.
  if (wave >= 2) {
    #pragma unroll
    for (int h = 0; h < NH; ++h)
      #pragma unroll
      for (int j = 0; j < 8; ++j)
        lds_xa[wave - 2][(h << 9) + lane * 8 + j] = xacc[h][j];
  }
  __syncthreads();
  if (wave < 2) {
    #pragma unroll
    for (int h = 0; h < NH; ++h)
      #pragma unroll
      for (int j = 0; j < 8; ++j)
        lds_xa[wave][(h << 9) + lane * 8 + j] += xacc[h][j];
  }
  __syncthreads();

  const int slot = blockIdx.x & (NSLOT - 1);
  if (threadIdx.x < NH) {
    const int h = threadIdx.x;
    atomicAdd(ws + WS_S + slot * NH + h,
              lds_s[0][h] + lds_s[1][h] + lds_s[2][h] + lds_s[3][h]);
  }
  #pragma unroll
  for (int j = 0; j < 8; ++j) {
    const int p = threadIdx.x + 256 * j;  // 0..2047, stride-1 across lanes
    atomicAdd(ws + WS_XA + slot * (NH * DIM) + p, lds_xa[0][p] + lds_xa[1][p]);
  }
}

// 512 blocks x 1 wave: one wave per output c. Sums the 32 xA/S slots inline.
__global__ __launch_bounds__(64)
void k_vproj(const float* __restrict__ ipw, const float* __restrict__ ipb,
             float* __restrict__ ws) {
  const int lane = threadIdx.x;
  const int c = blockIdx.x;  // 0..511
  const int h = c >> 7;
  float xs[8] = {0.f,0.f,0.f,0.f,0.f,0.f,0.f,0.f};
  #pragma unroll
  for (int sl = 0; sl < NSLOT; ++sl) {
    const float* xv = ws + WS_XA + sl * (NH * DIM) + h * DIM + lane * 8;
    const float4 a = *(const float4*)xv;
    const float4 b = *(const float4*)(xv + 4);
    xs[0]+=a.x; xs[1]+=a.y; xs[2]+=a.z; xs[3]+=a.w;
    xs[4]+=b.x; xs[5]+=b.y; xs[6]+=b.z; xs[7]+=b.w;
  }
  float S = 0.f;
  #pragma unroll
  for (int sl = 0; sl < NSLOT; ++sl) S += ws[WS_S + sl * NH + h];

  const float* wr = ipw + (size_t)(2 * DIM + c) * DIM + lane * 8;
  const float4 wa = *(const float4*)wr;
  const float4 wb = *(const float4*)(wr + 4);
  float acc = wa.x*xs[0] + wa.y*xs[1] + wa.z*xs[2] + wa.w*xs[3]
            + wb.x*xs[4] + wb.y*xs[5] + wb.z*xs[6] + wb.w*xs[7];
  #pragma unroll
  for (int off = 32; off; off >>= 1) acc += __shfl_xor(acc, off, 64);
  if (lane == 0)
    ws[WS_ATTN + c] = acc / S + ipb[2 * DIM + c];
}

// 512 blocks x 1 wave: one wave per output i.
__global__ __launch_bounds__(64)
void k_oproj(const float* __restrict__ opw, const float* __restrict__ opb,
             const float* __restrict__ ws, float* __restrict__ out) {
  const int lane = threadIdx.x;
  const int i = blockIdx.x;  // 0..511
  const float4 aa = *(const float4*)(ws + WS_ATTN + lane * 8);
  const float4 ab = *(const float4*)(ws + WS_ATTN + lane * 8 + 4);
  const float* wr = opw + (size_t)i * DIM + lane * 8;
  const float4 wa = *(const float4*)wr;
  const float4 wb = *(const float4*)(wr + 4);
  float acc = wa.x*aa.x + wa.y*aa.y + wa.z*aa.z + wa.w*aa.w
            + wb.x*ab.x + wb.y*ab.y + wb.z*ab.z + wb.w*ab.w;
  #pragma unroll
  for (int off = 32; off; off >>= 1) acc += __shfl_xor(acc, off, 64);
  if (lane == 0) out[i] = acc + opb[i];
}

extern "C" void kernel_launch(void* const* d_in, const int* in_sizes, int n_in,
                              void* d_out, int out_size, void* d_ws, size_t ws_size,
                              hipStream_t stream) {
  const float* x   = (const float*)d_in[0];
  const float* ipw = (const float*)d_in[1];
  const float* ipb = (const float*)d_in[2];
  const float* opw = (const float*)d_in[3];
  const float* opb = (const float*)d_in[4];
  float* out = (float*)d_out;
  float* ws  = (float*)d_ws;

  k_qproj<<<512, 64, 0, stream>>>(x, ipw, ipb, ws);
  k_qk   <<<256, 64, 0, stream>>>(ipw, ws);
  k_main <<<NB, 256, 0, stream>>>(x, ws);
  k_vproj<<<512, 64, 0, stream>>>(ipw, ipb, ws);
  k_oproj<<<512, 64, 0, stream>>>(opw, opb, ws, out);
}